// Round 3
// baseline (1814.998 us; speedup 1.0000x reference)
//
#include <hip/hip_runtime.h>
#include <hip/hip_bf16.h>

// ---- constants -------------------------------------------------------------
#define S_LEN 2048
#define EMB   2048
#define NH    16
#define HD    128

typedef __attribute__((ext_vector_type(8))) __bf16 bf16x8;
typedef __attribute__((ext_vector_type(8))) unsigned short ushort8;
typedef __attribute__((ext_vector_type(4))) float  floatx4;

// float -> bf16 bit pattern
__device__ inline unsigned short f2b(float f) {
    __hip_bfloat16 h = __float2bfloat16(f);
    return *reinterpret_cast<unsigned short*>(&h);
}
// bf16 bit pattern -> float (exact)
__device__ inline float b2f(unsigned short u) {
    union { unsigned int i; float f; } c;
    c.i = ((unsigned int)u) << 16;
    return c.f;
}

// ---- helpers ---------------------------------------------------------------
__device__ inline float wave_max(float v) {
    #pragma unroll
    for (int o = 32; o > 0; o >>= 1) v = fmaxf(v, __shfl_xor(v, o, 64));
    return v;
}
__device__ inline float wave_sum(float v) {
    #pragma unroll
    for (int o = 32; o > 0; o >>= 1) v += __shfl_xor(v, o, 64);
    return v;
}

// ---- GEMM: C[m][n] = sum_k A[m][k] * B[n][k]   (B supplied transposed) -----
// A: M x K, fp32 (A_IS_BF16=false) or bf16 (true), row-major.
// Bw: N x K fp32 row-major — converted to bf16 during LDS staging.
// If outHSD != null: write bf16 to [((n>>7)*S_LEN + m)*HD + (n&127)]  ([NH][S][HD])
// else:              write fp32 to outMN[m*N + n].
template <bool A_IS_BF16>
__global__ __launch_bounds__(256) void gemm_bt(
    const void* __restrict__ Av,
    const float* __restrict__ Bw,
    __hip_bfloat16* __restrict__ outHSD,
    float* __restrict__ outMN,
    int M, int N, int K)
{
    __shared__ __align__(16) unsigned short As[64][40];  // +8 pad: 80B stride (16B-mult)
    __shared__ __align__(16) unsigned short Bs[64][40];

    const int m0 = blockIdx.x * 64;
    const int n0 = blockIdx.y * 64;
    const int t    = threadIdx.x;
    const int lane = t & 63;
    const int wave = t >> 6;
    const int wm = (wave >> 1) * 32;   // wave quadrant within 64x64
    const int wn = (wave &  1) * 32;
    const int lr = lane & 15;          // row within 16 (A: m, B: n)
    const int q8 = (lane >> 4) * 8;    // k offset within 32

    // staging: 256 threads x 8 elements = 64x32 tile
    const int sr = t >> 2;             // 0..63
    const int sc = (t & 3) * 8;        // 0,8,16,24

    const floatx4 z = {0.f, 0.f, 0.f, 0.f};
    floatx4 acc00 = z, acc01 = z, acc10 = z, acc11 = z;

    for (int k0 = 0; k0 < K; k0 += 32) {
        ushort8 av, bv;
        if (A_IS_BF16) {
            av = *(const ushort8*)((const unsigned short*)Av
                                   + (size_t)(m0 + sr) * K + k0 + sc);
        } else {
            const float* Af = (const float*)Av;
            float4 lo = *(const float4*)(Af + (size_t)(m0 + sr) * K + k0 + sc);
            float4 hi = *(const float4*)(Af + (size_t)(m0 + sr) * K + k0 + sc + 4);
            av[0] = f2b(lo.x); av[1] = f2b(lo.y); av[2] = f2b(lo.z); av[3] = f2b(lo.w);
            av[4] = f2b(hi.x); av[5] = f2b(hi.y); av[6] = f2b(hi.z); av[7] = f2b(hi.w);
        }
        {
            float4 lo = *(const float4*)(Bw + (size_t)(n0 + sr) * K + k0 + sc);
            float4 hi = *(const float4*)(Bw + (size_t)(n0 + sr) * K + k0 + sc + 4);
            bv[0] = f2b(lo.x); bv[1] = f2b(lo.y); bv[2] = f2b(lo.z); bv[3] = f2b(lo.w);
            bv[4] = f2b(hi.x); bv[5] = f2b(hi.y); bv[6] = f2b(hi.z); bv[7] = f2b(hi.w);
        }
        __syncthreads();                      // prior iter's LDS reads done
        *(ushort8*)&As[sr][sc] = av;
        *(ushort8*)&Bs[sr][sc] = bv;
        __syncthreads();                      // stores visible

        bf16x8 a0 = *(const bf16x8*)&As[wm      + lr][q8];
        bf16x8 a1 = *(const bf16x8*)&As[wm + 16 + lr][q8];
        bf16x8 b0 = *(const bf16x8*)&Bs[wn      + lr][q8];
        bf16x8 b1 = *(const bf16x8*)&Bs[wn + 16 + lr][q8];

        acc00 = __builtin_amdgcn_mfma_f32_16x16x32_bf16(a0, b0, acc00, 0, 0, 0);
        acc01 = __builtin_amdgcn_mfma_f32_16x16x32_bf16(a0, b1, acc01, 0, 0, 0);
        acc10 = __builtin_amdgcn_mfma_f32_16x16x32_bf16(a1, b0, acc10, 0, 0, 0);
        acc11 = __builtin_amdgcn_mfma_f32_16x16x32_bf16(a1, b1, acc11, 0, 0, 0);
    }

    // epilogue: C/D layout col = lane&15, row = (lane>>4)*4 + r  [m89/m91]
    const int rbase = (lane >> 4) * 4;
    const int cbase = lane & 15;
    #pragma unroll
    for (int i = 0; i < 2; i++) {
        #pragma unroll
        for (int j = 0; j < 2; j++) {
            floatx4 a = (i == 0) ? (j == 0 ? acc00 : acc01)
                                 : (j == 0 ? acc10 : acc11);
            #pragma unroll
            for (int r = 0; r < 4; r++) {
                int row = m0 + wm + i * 16 + rbase + r;
                int col = n0 + wn + j * 16 + cbase;
                if (outHSD) {
                    int h = col >> 7, dd = col & 127;
                    outHSD[((size_t)h * S_LEN + row) * HD + dd] = __float2bfloat16(a[r]);
                } else {
                    outMN[(size_t)row * N + col] = a[r];
                }
            }
        }
    }
}

// ---- RoPE on Q and K in place (bf16, (h,s,d) layout); cos/sin fp32 ---------
// q'[d]      = q[d]*cos[d]       - q[d+64]*sin[d]       (d < 64)
// q'[d+64]   = q[d+64]*cos[d+64] + q[d]*sin[d+64]
__global__ __launch_bounds__(64) void rope_kernel(
    __hip_bfloat16* __restrict__ q, __hip_bfloat16* __restrict__ k,
    const float* __restrict__ cosf,
    const float* __restrict__ sinf)
{
    const int s = blockIdx.x, h = blockIdx.y;
    __hip_bfloat16* base = (blockIdx.z ? k : q) + ((size_t)h * S_LEN + s) * HD;
    const int l = threadIdx.x;  // 0..63
    float c0 = cosf[s * HD + l];
    float c1 = cosf[s * HD + 64 + l];
    float s0 = sinf[s * HD + l];
    float s1 = sinf[s * HD + 64 + l];
    float x0 = __bfloat162float(base[l]);
    float x1 = __bfloat162float(base[64 + l]);
    base[l]      = __float2bfloat16(x0 * c0 - x1 * s0);
    base[64 + l] = __float2bfloat16(x1 * c1 + x0 * s1);
}

// ---- causal attention: one wave per (head, query row), online softmax ------
// q/k/v bf16 (h,s,d); output bf16 in (s, h*HD + d) layout (= transpose-merge).
__global__ __launch_bounds__(64) void attn_kernel(
    const __hip_bfloat16* __restrict__ qb, const __hip_bfloat16* __restrict__ kb,
    const __hip_bfloat16* __restrict__ vb, __hip_bfloat16* __restrict__ attnb)
{
    const int qi = blockIdx.x, h = blockIdx.y;
    const int l  = threadIdx.x;
    __shared__ float qsh[HD];
    __shared__ float psh[64];

    const size_t hb = (size_t)h * S_LEN;
    const __hip_bfloat16* qrow = qb + (hb + qi) * HD;
    qsh[l]      = __bfloat162float(qrow[l]);
    qsh[64 + l] = __bfloat162float(qrow[64 + l]);
    __syncthreads();

    const float scale = 0.08838834764831845f;  // 1/sqrt(128)
    float m = -1e30f, lsum = 0.f, acc0 = 0.f, acc1 = 0.f;

    for (int jb = 0; jb <= qi; jb += 64) {
        const int j = jb + l;
        float sc = -1e30f;
        if (j <= qi) {
            const ushort8* kr = (const ushort8*)(kb + (hb + j) * HD);  // 256B-aligned
            float d0 = 0.f;
            #pragma unroll
            for (int c = 0; c < 16; c++) {
                ushort8 kv = kr[c];
                #pragma unroll
                for (int e = 0; e < 8; e++)
                    d0 += qsh[c * 8 + e] * b2f(kv[e]);
            }
            sc = d0 * scale;
        }
        const float bm = wave_max(sc);
        const float mn = fmaxf(m, bm);
        const float p  = (j <= qi) ? __expf(sc - mn) : 0.f;
        const float alpha = __expf(m - mn);  // exp(-huge)=0 on first iter
        lsum = lsum * alpha + wave_sum(p);
        acc0 *= alpha;
        acc1 *= alpha;

        __syncthreads();           // protect psh from prior iter's reads
        psh[l] = p;
        __syncthreads();

        const int cnt = min(64, qi - jb + 1);
        const __hip_bfloat16* vbase = vb + (hb + jb) * HD;
        for (int j2 = 0; j2 < cnt; j2++) {
            const float pj = psh[j2];
            acc0 += pj * __bfloat162float(vbase[j2 * HD + l]);
            acc1 += pj * __bfloat162float(vbase[j2 * HD + 64 + l]);
        }
        m = mn;
    }

    const float inv = 1.f / lsum;
    attnb[(size_t)qi * EMB + h * HD + l]      = __float2bfloat16(acc0 * inv);
    attnb[(size_t)qi * EMB + h * HD + 64 + l] = __float2bfloat16(acc1 * inv);
}

// ---- launch ---------------------------------------------------------------
extern "C" void kernel_launch(void* const* d_in, const int* in_sizes, int n_in,
                              void* d_out, int out_size, void* d_ws, size_t ws_size,
                              hipStream_t stream) {
    const float* x  = (const float*)d_in[0];
    const float* rc = (const float*)d_in[1];
    const float* rs = (const float*)d_in[2];
    const float* Wq = (const float*)d_in[3];
    const float* Wk = (const float*)d_in[4];
    const float* Wv = (const float*)d_in[5];
    const float* Wo = (const float*)d_in[6];
    float* out = (float*)d_out;

    // ws: 4 x 8 MB bf16 buffers = 32 MB total
    char* ws = (char*)d_ws;
    __hip_bfloat16* qbuf  = (__hip_bfloat16*)(ws);                       // (h,s,d)
    __hip_bfloat16* kbuf  = (__hip_bfloat16*)(ws + (size_t)( 8u << 20)); // (h,s,d)
    __hip_bfloat16* vbuf  = (__hip_bfloat16*)(ws + (size_t)(16u << 20)); // (h,s,d)
    __hip_bfloat16* attnb = (__hip_bfloat16*)(ws + (size_t)(24u << 20)); // (s, h*d)

    dim3 gg(32, 32, 1), gb(256, 1, 1);
    hipLaunchKernelGGL((gemm_bt<false>), gg, gb, 0, stream,
                       (const void*)x, Wq, qbuf, (float*)nullptr, S_LEN, EMB, EMB);
    hipLaunchKernelGGL((gemm_bt<false>), gg, gb, 0, stream,
                       (const void*)x, Wk, kbuf, (float*)nullptr, S_LEN, EMB, EMB);
    hipLaunchKernelGGL((gemm_bt<false>), gg, gb, 0, stream,
                       (const void*)x, Wv, vbuf, (float*)nullptr, S_LEN, EMB, EMB);

    hipLaunchKernelGGL(rope_kernel, dim3(S_LEN, NH, 2), dim3(64), 0, stream,
                       qbuf, kbuf, rc, rs);

    hipLaunchKernelGGL(attn_kernel, dim3(S_LEN, NH), dim3(64), 0, stream,
                       qbuf, kbuf, vbuf, attnb);

    hipLaunchKernelGGL((gemm_bt<true>), gg, gb, 0, stream,
                       (const void*)attnb, Wo, (__hip_bfloat16*)nullptr, out,
                       S_LEN, EMB, EMB);
}

// Round 4
// 529.194 us; speedup vs baseline: 3.4297x; 3.4297x over previous
//
#include <hip/hip_runtime.h>
#include <hip/hip_bf16.h>

// ---- constants -------------------------------------------------------------
#define S_LEN 2048
#define EMB   2048
#define NH    16
#define HD    128

typedef __attribute__((ext_vector_type(8))) __bf16 bf16x8;
typedef __attribute__((ext_vector_type(8))) unsigned short ushort8;
typedef __attribute__((ext_vector_type(4))) float  floatx4;

// float -> bf16 bits
__device__ inline unsigned short f2b(float f) {
    __hip_bfloat16 h = __float2bfloat16(f);
    return *reinterpret_cast<unsigned short*>(&h);
}

// ---- GEMM: C[m][n] = sum_k A[m][k] * B[n][k]   (B supplied transposed) -----
// A: M x K, fp32 (A_IS_BF16=false) or bf16 (true), row-major.
// Bw: N x K fp32 row-major — converted to bf16 during LDS staging.
// If outHSD != null: write bf16 to [((n>>7)*S_LEN + m)*HD + (n&127)]  ([NH][S][HD])
// else:              write fp32 to outMN[m*N + n].
template <bool A_IS_BF16>
__global__ __launch_bounds__(256) void gemm_bt(
    const void* __restrict__ Av,
    const float* __restrict__ Bw,
    __hip_bfloat16* __restrict__ outHSD,
    float* __restrict__ outMN,
    int M, int N, int K)
{
    __shared__ __align__(16) unsigned short As[64][40];
    __shared__ __align__(16) unsigned short Bs[64][40];

    const int m0 = blockIdx.x * 64;
    const int n0 = blockIdx.y * 64;
    const int t    = threadIdx.x;
    const int lane = t & 63;
    const int wave = t >> 6;
    const int wm = (wave >> 1) * 32;
    const int wn = (wave &  1) * 32;
    const int lr = lane & 15;
    const int q8 = (lane >> 4) * 8;

    const int sr = t >> 2;
    const int sc = (t & 3) * 8;

    const floatx4 z = {0.f, 0.f, 0.f, 0.f};
    floatx4 acc00 = z, acc01 = z, acc10 = z, acc11 = z;

    for (int k0 = 0; k0 < K; k0 += 32) {
        ushort8 av, bv;
        if (A_IS_BF16) {
            av = *(const ushort8*)((const unsigned short*)Av
                                   + (size_t)(m0 + sr) * K + k0 + sc);
        } else {
            const float* Af = (const float*)Av;
            float4 lo = *(const float4*)(Af + (size_t)(m0 + sr) * K + k0 + sc);
            float4 hi = *(const float4*)(Af + (size_t)(m0 + sr) * K + k0 + sc + 4);
            av[0] = f2b(lo.x); av[1] = f2b(lo.y); av[2] = f2b(lo.z); av[3] = f2b(lo.w);
            av[4] = f2b(hi.x); av[5] = f2b(hi.y); av[6] = f2b(hi.z); av[7] = f2b(hi.w);
        }
        {
            float4 lo = *(const float4*)(Bw + (size_t)(n0 + sr) * K + k0 + sc);
            float4 hi = *(const float4*)(Bw + (size_t)(n0 + sr) * K + k0 + sc + 4);
            bv[0] = f2b(lo.x); bv[1] = f2b(lo.y); bv[2] = f2b(lo.z); bv[3] = f2b(lo.w);
            bv[4] = f2b(hi.x); bv[5] = f2b(hi.y); bv[6] = f2b(hi.z); bv[7] = f2b(hi.w);
        }
        __syncthreads();
        *(ushort8*)&As[sr][sc] = av;
        *(ushort8*)&Bs[sr][sc] = bv;
        __syncthreads();

        bf16x8 a0 = *(const bf16x8*)&As[wm      + lr][q8];
        bf16x8 a1 = *(const bf16x8*)&As[wm + 16 + lr][q8];
        bf16x8 b0 = *(const bf16x8*)&Bs[wn      + lr][q8];
        bf16x8 b1 = *(const bf16x8*)&Bs[wn + 16 + lr][q8];

        acc00 = __builtin_amdgcn_mfma_f32_16x16x32_bf16(a0, b0, acc00, 0, 0, 0);
        acc01 = __builtin_amdgcn_mfma_f32_16x16x32_bf16(a0, b1, acc01, 0, 0, 0);
        acc10 = __builtin_amdgcn_mfma_f32_16x16x32_bf16(a1, b0, acc10, 0, 0, 0);
        acc11 = __builtin_amdgcn_mfma_f32_16x16x32_bf16(a1, b1, acc11, 0, 0, 0);
    }

    const int rbase = (lane >> 4) * 4;
    const int cbase = lane & 15;
    #pragma unroll
    for (int i = 0; i < 2; i++) {
        #pragma unroll
        for (int j = 0; j < 2; j++) {
            floatx4 a = (i == 0) ? (j == 0 ? acc00 : acc01)
                                 : (j == 0 ? acc10 : acc11);
            #pragma unroll
            for (int r = 0; r < 4; r++) {
                int row = m0 + wm + i * 16 + rbase + r;
                int col = n0 + wn + j * 16 + cbase;
                if (outHSD) {
                    int h = col >> 7, dd = col & 127;
                    outHSD[((size_t)h * S_LEN + row) * HD + dd] = __float2bfloat16(a[r]);
                } else {
                    outMN[(size_t)row * N + col] = a[r];
                }
            }
        }
    }
}

// ---- RoPE on Q and K in place (bf16, (h,s,d) layout); cos/sin fp32 ---------
__global__ __launch_bounds__(64) void rope_kernel(
    __hip_bfloat16* __restrict__ q, __hip_bfloat16* __restrict__ k,
    const float* __restrict__ cosf,
    const float* __restrict__ sinf)
{
    const int s = blockIdx.x, h = blockIdx.y;
    __hip_bfloat16* base = (blockIdx.z ? k : q) + ((size_t)h * S_LEN + s) * HD;
    const int l = threadIdx.x;  // 0..63
    float c0 = cosf[s * HD + l];
    float c1 = cosf[s * HD + 64 + l];
    float s0 = sinf[s * HD + l];
    float s1 = sinf[s * HD + 64 + l];
    float x0 = __bfloat162float(base[l]);
    float x1 = __bfloat162float(base[64 + l]);
    base[l]      = __float2bfloat16(x0 * c0 - x1 * s0);
    base[64 + l] = __float2bfloat16(x1 * c1 + x0 * s1);
}

// ---- flash attention, MFMA (16x16x32 bf16) ---------------------------------
// Block: 256 thr = 4 waves; 64 q-rows per block (16 per wave), one head.
// K-tiles of 64 keys. Q/K fragments from global; V staged to LDS transposed
// with XOR swizzle; P round-trips C-layout -> A-layout through per-wave LDS.
__global__ __launch_bounds__(256) void flash_attn(
    const __hip_bfloat16* __restrict__ qb, const __hip_bfloat16* __restrict__ kb,
    const __hip_bfloat16* __restrict__ vb, __hip_bfloat16* __restrict__ attnb)
{
    __shared__ __align__(16) unsigned short Vt[HD][72];     // [d][swizzled j]
    __shared__ __align__(16) unsigned short Ps[4][16][72];  // per-wave P tile

    const int q0 = blockIdx.x * 64;
    const int h  = blockIdx.y;
    const int t    = threadIdx.x;
    const int lane = t & 63;
    const int w    = t >> 6;
    const size_t hb = (size_t)h * S_LEN;

    const int l15 = lane & 15;
    const int g4  = lane >> 4;          // 0..3
    const int koff = g4 * 8;

    // Q fragments: A[m=l15][k=g4*8+e (+32kk)], rows q0+16w+l15
    bf16x8 qf[4];
    const __hip_bfloat16* qrow = qb + (hb + q0 + w * 16 + l15) * HD;
    #pragma unroll
    for (int kk = 0; kk < 4; kk++)
        qf[kk] = *(const bf16x8*)(qrow + kk * 32 + koff);

    const floatx4 z = {0.f, 0.f, 0.f, 0.f};
    floatx4 O[8] = {z, z, z, z, z, z, z, z};
    float mrow[4] = {-1e30f, -1e30f, -1e30f, -1e30f};
    float lrow[4] = {0.f, 0.f, 0.f, 0.f};

    const float scale = 0.08838834764831845f;  // 1/sqrt(128)
    const int qg_base = q0 + w * 16 + g4 * 4;  // this lane's q rows: +r

    for (int jb0 = 0; jb0 <= q0; jb0 += 64) {
        __syncthreads();   // prior iter's Vt reads done
        // ---- stage V tile transposed+swizzled: Vt[d][pc(j)] = V[jb0+j][d]
        #pragma unroll
        for (int it = 0; it < 4; it++) {
            const int j  = it * 16 + (t >> 4);
            const int d0 = (t & 15) * 8;
            ushort8 vv = *(const ushort8*)(vb + (hb + jb0 + j) * HD + d0);
            const int pc = ((((j >> 3) ^ (t & 7)) << 3) | (j & 7));
            #pragma unroll
            for (int e = 0; e < 8; e++)
                Vt[d0 + e][pc] = vv[e];
        }
        __syncthreads();

        // ---- scores: S[q16][64] = Q . K^T, K B-frags from global
        floatx4 sc[4];
        #pragma unroll
        for (int jb = 0; jb < 4; jb++) {
            floatx4 acc = z;
            const __hip_bfloat16* krow = kb + (hb + jb0 + jb * 16 + l15) * HD + koff;
            #pragma unroll
            for (int kk = 0; kk < 4; kk++) {
                bf16x8 kf = *(const bf16x8*)(krow + kk * 32);
                acc = __builtin_amdgcn_mfma_f32_16x16x32_bf16(qf[kk], kf, acc, 0, 0, 0);
            }
            sc[jb] = acc;
        }

        // ---- scale + causal mask (diagonal tile only)
        const bool diag = (jb0 == q0);
        #pragma unroll
        for (int jb = 0; jb < 4; jb++) {
            #pragma unroll
            for (int r = 0; r < 4; r++) {
                float s = sc[jb][r] * scale;
                if (diag && (jb * 16 + l15) > (w * 16 + g4 * 4 + r)) s = -1e30f;
                sc[jb][r] = s;
            }
        }

        // ---- online softmax (per q row; 16-lane group reductions)
        float alpha[4];
        #pragma unroll
        for (int r = 0; r < 4; r++) {
            float rm = fmaxf(fmaxf(sc[0][r], sc[1][r]), fmaxf(sc[2][r], sc[3][r]));
            #pragma unroll
            for (int o = 1; o < 16; o <<= 1) rm = fmaxf(rm, __shfl_xor(rm, o, 64));
            const float mn = fmaxf(mrow[r], rm);
            alpha[r] = __expf(mrow[r] - mn);
            float ps = 0.f;
            #pragma unroll
            for (int jb = 0; jb < 4; jb++) {
                float p = __expf(sc[jb][r] - mn);
                sc[jb][r] = p;
                ps += p;
            }
            #pragma unroll
            for (int o = 1; o < 16; o <<= 1) ps += __shfl_xor(ps, o, 64);
            lrow[r] = lrow[r] * alpha[r] + ps;
            mrow[r] = mn;
        }
        #pragma unroll
        for (int db = 0; db < 8; db++)
            #pragma unroll
            for (int r = 0; r < 4; r++)
                O[db][r] *= alpha[r];

        // ---- P: C-layout -> LDS (per-wave) -> A-layout
        #pragma unroll
        for (int jb = 0; jb < 4; jb++)
            #pragma unroll
            for (int r = 0; r < 4; r++)
                Ps[w][g4 * 4 + r][jb * 16 + l15] = f2b(sc[jb][r]);
        __syncthreads();   // orders Ps write->read (and aligns waves)

        // ---- O += P . V
        #pragma unroll
        for (int half = 0; half < 2; half++) {
            bf16x8 af = *(const bf16x8*)&Ps[w][l15][half * 32 + koff];
            #pragma unroll
            for (int db = 0; db < 8; db++) {
                const int d  = db * 16 + l15;
                const int pg = ((half * 4 + g4) ^ ((d >> 3) & 7)) << 3;
                bf16x8 bf = *(const bf16x8*)&Vt[d][pg];
                O[db] = __builtin_amdgcn_mfma_f32_16x16x32_bf16(af, bf, O[db], 0, 0, 0);
            }
        }
    }

    // ---- epilogue: O /= l, write (s, h*HD+d)
    float inv[4];
    #pragma unroll
    for (int r = 0; r < 4; r++) inv[r] = 1.f / lrow[r];
    #pragma unroll
    for (int db = 0; db < 8; db++) {
        #pragma unroll
        for (int r = 0; r < 4; r++) {
            const int row = qg_base + r;
            const int col = h * HD + db * 16 + l15;
            attnb[(size_t)row * EMB + col] = __float2bfloat16(O[db][r] * inv[r]);
        }
    }
}

// ---- launch ---------------------------------------------------------------
extern "C" void kernel_launch(void* const* d_in, const int* in_sizes, int n_in,
                              void* d_out, int out_size, void* d_ws, size_t ws_size,
                              hipStream_t stream) {
    const float* x  = (const float*)d_in[0];
    const float* rc = (const float*)d_in[1];
    const float* rs = (const float*)d_in[2];
    const float* Wq = (const float*)d_in[3];
    const float* Wk = (const float*)d_in[4];
    const float* Wv = (const float*)d_in[5];
    const float* Wo = (const float*)d_in[6];
    float* out = (float*)d_out;

    // ws: 4 x 8 MB bf16 buffers = 32 MB total
    char* ws = (char*)d_ws;
    __hip_bfloat16* qbuf  = (__hip_bfloat16*)(ws);                       // (h,s,d)
    __hip_bfloat16* kbuf  = (__hip_bfloat16*)(ws + (size_t)( 8u << 20)); // (h,s,d)
    __hip_bfloat16* vbuf  = (__hip_bfloat16*)(ws + (size_t)(16u << 20)); // (h,s,d)
    __hip_bfloat16* attnb = (__hip_bfloat16*)(ws + (size_t)(24u << 20)); // (s, h*d)

    dim3 gg(32, 32, 1), gb(256, 1, 1);
    hipLaunchKernelGGL((gemm_bt<false>), gg, gb, 0, stream,
                       (const void*)x, Wq, qbuf, (float*)nullptr, S_LEN, EMB, EMB);
    hipLaunchKernelGGL((gemm_bt<false>), gg, gb, 0, stream,
                       (const void*)x, Wk, kbuf, (float*)nullptr, S_LEN, EMB, EMB);
    hipLaunchKernelGGL((gemm_bt<false>), gg, gb, 0, stream,
                       (const void*)x, Wv, vbuf, (float*)nullptr, S_LEN, EMB, EMB);

    hipLaunchKernelGGL(rope_kernel, dim3(S_LEN, NH, 2), dim3(64), 0, stream,
                       qbuf, kbuf, rc, rs);

    hipLaunchKernelGGL(flash_attn, dim3(S_LEN / 64, NH), dim3(256), 0, stream,
                       qbuf, kbuf, vbuf, attnb);

    hipLaunchKernelGGL((gemm_bt<true>), gg, gb, 0, stream,
                       (const void*)attnb, Wo, (__hip_bfloat16*)nullptr, out,
                       S_LEN, EMB, EMB);
}